// Round 8
// baseline (1137.304 us; speedup 1.0000x reference)
//
#include <hip/hip_runtime.h>
#include <hip/hip_bf16.h>
#include <string.h>

// Problem constants
#define B_ 4
#define D_ 256
#define H_ 8
#define HD_ 32
#define L_ 4
#define P_ 4
#define NL_ 6
#define FF_ 1024
#define LQ_ 5440
#define M_ (B_ * LQ_)   // 21760 = 170*128 = 340*64 = 680*32

typedef __attribute__((ext_vector_type(8))) short short8;
typedef __attribute__((ext_vector_type(4))) float f32x4;

// per-layer transposed-weight block (bf16), [N][K] k-contig:
//   OAV (640 x 256)  ofs 0      (0-255 Woff, 256-383 Wattn, 384-639 Wv)
//   O   (256 x 256)  ofs 163840
//   FC1 (1024 x 256) ofs 229376
//   FC2 (256 x 1024) ofs 491520
#define WL_ 753664
#define WOFS_OAV 0
#define WOFS_V   98304   // = 384*256, V sub-block inside OAV
#define WOFS_O   163840
#define WOFS_F1  229376
#define WOFS_F2  491520

// ---------------------------------------------------------------------------
__device__ __forceinline__ float ldin(const void* p, size_t i, int isb) {
    if (isb) return __bfloat162float(((const __hip_bfloat16*)p)[i]);
    return ((const float*)p)[i];
}
__device__ __forceinline__ float bfu2f(unsigned short u) {
    __hip_bfloat16 h; memcpy(&h, &u, 2); return __bfloat162float(h);
}
__device__ __forceinline__ unsigned short f2bfu(float f) {
    __hip_bfloat16 h = __float2bfloat16(f);
    unsigned short u; memcpy(&u, &h, 2); return u;
}

__global__ void detect_kernel(const unsigned int* __restrict__ g, int* __restrict__ flag) {
    *flag = (g[0] == 0x3F800000u) ? 0 : 1;
}

// level tables: shapes (64,64),(32,32),(16,16),(8,8); starts 0,4096,5120,5376
__device__ __forceinline__ void decode_q(int q, int& l, int& y, int& x) {
    if (q < 4096)      { l = 0; y = q >> 6; x = q & 63; }
    else if (q < 5120) { q -= 4096; l = 1; y = q >> 5; x = q & 31; }
    else if (q < 5376) { q -= 5120; l = 2; y = q >> 4; x = q & 15; }
    else               { q -= 5376; l = 3; y = q >> 3; x = q & 7;  }
}

// supertile swizzle (XCD L2 locality): groups of 8 m-stripes x all n-tiles.
__device__ __forceinline__ void swz(int flat, int ytiles, int nX, int& by, int& bx) {
    int sgsize = 8 * nX;
    int sg = flat / sgsize, rem = flat % sgsize;
    int h8 = ytiles - sg * 8; if (h8 > 8) h8 = 8;
    by = sg * 8 + rem % h8;
    bx = rem / h8;
}

// ---------------------------------------------------------------------------
// weight transpose: W[K][N1]+W[K][N2] (concat cols) -> dst[n][k] bf16
// ---------------------------------------------------------------------------
__global__ __launch_bounds__(256) void transpose_kernel(
    const void* __restrict__ W1, int w1ls, int N1,
    const void* __restrict__ W2, int w2ls, int N2,
    int K, __hip_bfloat16* __restrict__ dst, int dofs,
    const int* __restrict__ dflag)
{
    const int isb = *dflag;
    const int layer = blockIdx.z;
    const int bn = blockIdx.x * 32, bk = blockIdx.y * 32;
    const int t = threadIdx.x;
    __shared__ unsigned short tile[32][33];
    const int nl = t & 31;
    #pragma unroll
    for (int i = 0; i < 4; ++i) {
        int kl = (t >> 5) + i * 8;
        int n = bn + nl, k = bk + kl;
        float v;
        if (n < N1) v = ldin(W1, (size_t)layer * w1ls + (size_t)k * N1 + n, isb);
        else        v = ldin(W2, (size_t)layer * w2ls + (size_t)k * N2 + (n - N1), isb);
        tile[kl][nl] = f2bfu(v);
    }
    __syncthreads();
    #pragma unroll
    for (int i = 0; i < 4; ++i) {
        int nl2 = (t >> 5) + i * 8;
        int n = bn + nl2, k = bk + (t & 31);
        unsigned short u = tile[t & 31][nl2];
        memcpy(&dst[(size_t)layer * WL_ + dofs + (size_t)n * K + k], &u, 2);
    }
}

// ---------------------------------------------------------------------------
// init v3: block = 64 pixels x 256 ch of one level, vectorized both sides.
// ---------------------------------------------------------------------------
__global__ __launch_bounds__(256) void init_kernel(
    const void* __restrict__ s0, const void* __restrict__ s1,
    const void* __restrict__ s2, const void* __restrict__ s3,
    const void* __restrict__ p0, const void* __restrict__ p1,
    const void* __restrict__ p2, const void* __restrict__ p3,
    const void* __restrict__ lvl_emb,
    float* __restrict__ cur, __hip_bfloat16* __restrict__ curb,
    __hip_bfloat16* __restrict__ posb,
    const int* __restrict__ dflag)
{
    const int isb = *dflag;
    const int tid = threadIdx.x;
    int blk = blockIdx.x;            // 0..339
    int b = blk / 85, t = blk % 85;
    int l, pix0, HW, start;
    if (t < 64)      { l = 0; pix0 = t * 64;        HW = 4096; start = 0; }
    else if (t < 80) { l = 1; pix0 = (t - 64) * 64; HW = 1024; start = 4096; }
    else if (t < 84) { l = 2; pix0 = (t - 80) * 64; HW = 256;  start = 5120; }
    else             { l = 3; pix0 = 0;             HW = 64;   start = 5376; }
    const void* sp = (l == 0) ? s0 : (l == 1) ? s1 : (l == 2) ? s2 : s3;
    const void* pp = (l == 0) ? p0 : (l == 1) ? p1 : (l == 2) ? p2 : p3;
    const int rowbase = b * LQ_ + start + pix0;

    __shared__ float tile[32][68];
    #pragma unroll
    for (int pass = 0; pass < 2; ++pass) {
        const void* gp = pass ? pp : sp;
        for (int ct = 0; ct < 8; ++ct) {
            __syncthreads();
            {   // read 32ch x 64pix (float4/ushort4 along pixels)
                int pl4 = (tid & 15) * 4;
                #pragma unroll
                for (int s = 0; s < 2; ++s) {
                    int cl = (tid >> 4) + s * 16;
                    size_t gi = ((size_t)b * 256 + ct * 32 + cl) * (size_t)HW + pix0 + pl4;
                    float4 v;
                    if (isb) {
                        ushort4 u = *(const ushort4*)((const unsigned short*)gp + gi);
                        v.x = bfu2f(u.x); v.y = bfu2f(u.y); v.z = bfu2f(u.z); v.w = bfu2f(u.w);
                    } else {
                        v = *(const float4*)((const float*)gp + gi);
                    }
                    tile[cl][pl4 + 0] = v.x; tile[cl][pl4 + 1] = v.y;
                    tile[cl][pl4 + 2] = v.z; tile[cl][pl4 + 3] = v.w;
                }
            }
            __syncthreads();
            {   // write: 32 pix-rows x 8 ch-quads (float4/ushort4 along ch)
                int cq = tid & 7, c4 = ct * 32 + cq * 4;
                #pragma unroll
                for (int s = 0; s < 2; ++s) {
                    int prow = (tid >> 3) + s * 32;
                    float4 ov;
                    ov.x = tile[cq * 4 + 0][prow]; ov.y = tile[cq * 4 + 1][prow];
                    ov.z = tile[cq * 4 + 2][prow]; ov.w = tile[cq * 4 + 3][prow];
                    size_t di = (size_t)(rowbase + prow) * 256 + c4;
                    if (pass == 0) {
                        *(float4*)(cur + di) = ov;
                        ushort4 ob;
                        ob.x = f2bfu(ov.x); ob.y = f2bfu(ov.y);
                        ob.z = f2bfu(ov.z); ob.w = f2bfu(ov.w);
                        *(ushort4*)((unsigned short*)curb + di) = ob;
                    } else {
                        ushort4 ob;
                        ob.x = f2bfu(ov.x + ldin(lvl_emb, l * 256 + c4 + 0, isb));
                        ob.y = f2bfu(ov.y + ldin(lvl_emb, l * 256 + c4 + 1, isb));
                        ob.z = f2bfu(ov.z + ldin(lvl_emb, l * 256 + c4 + 2, isb));
                        ob.w = f2bfu(ov.w + ldin(lvl_emb, l * 256 + c4 + 3, isb));
                        *(ushort4*)((unsigned short*)posb + di) = ob;
                    }
                }
            }
        }
    }
}

// ---------------------------------------------------------------------------
// MFMA GEMM 128x128 (fc1): BK=64, 4 waves (2x2), wave 64x64. A bf16.
// ---------------------------------------------------------------------------
#define LDSP 72
__global__ __launch_bounds__(256) void gemm_mfma(
    const unsigned short* __restrict__ A, int lda,
    const __hip_bfloat16* __restrict__ Wt,
    const void* __restrict__ bias, size_t bofs,
    void* __restrict__ C, int c_bf16, int ldc,
    int N, int K, int relu, int ytiles, int nX, const int* __restrict__ dflag)
{
    const int isb = *dflag;
    __shared__ __align__(16) unsigned short As[128 * LDSP];
    __shared__ __align__(16) unsigned short Bs[128 * LDSP];
    int byi, bxi; swz(blockIdx.x, ytiles, nX, byi, bxi);
    const int bm = byi * 128, bn = bxi * 128;
    const int tid = threadIdx.x;
    const int lane = tid & 63, w = tid >> 6;
    const int quad = lane >> 4, l15 = lane & 15;
    const int wm = w & 1, wn = w >> 1;

    f32x4 acc[4][4];
    #pragma unroll
    for (int i = 0; i < 4; ++i)
        #pragma unroll
        for (int j = 0; j < 4; ++j)
            acc[i][j] = (f32x4){0.f, 0.f, 0.f, 0.f};

    const int ak4 = tid & 15, ar = tid >> 4;
    const int bk8 = tid & 7,  bnr = tid >> 3;

    for (int k0 = 0; k0 < K; k0 += 64) {
        #pragma unroll
        for (int i = 0; i < 8; ++i) {
            int rr = ar + i * 16;
            ushort4 o = *(const ushort4*)(A + (size_t)(bm + rr) * lda + k0 + ak4 * 4);
            *(ushort4*)(&As[rr * LDSP + ak4 * 4]) = o;
        }
        #pragma unroll
        for (int i = 0; i < 4; ++i) {
            int nn = bnr + i * 32;
            uint4 xv = *(const uint4*)((const unsigned short*)Wt +
                    (size_t)(bn + nn) * K + k0 + bk8 * 8);
            *(uint4*)(&Bs[nn * LDSP + bk8 * 8]) = xv;
        }
        __syncthreads();
        #pragma unroll
        for (int kk = 0; kk < 64; kk += 32) {
            short8 af[4], bf[4];
            #pragma unroll
            for (int mt = 0; mt < 4; ++mt)
                af[mt] = *(const short8*)(&As[(wm * 64 + mt * 16 + l15) * LDSP + kk + quad * 8]);
            #pragma unroll
            for (int nt = 0; nt < 4; ++nt)
                bf[nt] = *(const short8*)(&Bs[(wn * 64 + nt * 16 + l15) * LDSP + kk + quad * 8]);
            #pragma unroll
            for (int mt = 0; mt < 4; ++mt)
                #pragma unroll
                for (int nt = 0; nt < 4; ++nt)
                    acc[mt][nt] = __builtin_amdgcn_mfma_f32_16x16x32_bf16(
                        af[mt], bf[nt], acc[mt][nt], 0, 0, 0);
        }
        __syncthreads();
    }

    #pragma unroll
    for (int nt = 0; nt < 4; ++nt) {
        int gcol = bn + wn * 64 + nt * 16 + l15;
        float bv = ldin(bias, bofs + gcol, isb);
        #pragma unroll
        for (int mt = 0; mt < 4; ++mt) {
            #pragma unroll
            for (int r = 0; r < 4; ++r) {
                int grow = bm + wm * 64 + mt * 16 + quad * 4 + r;
                float v = acc[mt][nt][r] + bv;
                if (relu) v = fmaxf(v, 0.f);
                if (c_bf16)
                    ((__hip_bfloat16*)C)[(size_t)grow * ldc + gcol] = __float2bfloat16(v);
                else
                    ((float*)C)[(size_t)grow * ldc + gcol] = v;
            }
        }
    }
}

// ---------------------------------------------------------------------------
// gemm_oav: tile 64x128 over N=640. cols 0-383: A=curb+posb, [Woff|Wattn];
// cols 384-639: A=curb, Wv. C split: pool [M,384] bf16 / vb [M,256] bf16.
// ---------------------------------------------------------------------------
__global__ __launch_bounds__(256) void gemm_oav(
    const unsigned short* __restrict__ curb,
    const unsigned short* __restrict__ posb,
    const __hip_bfloat16* __restrict__ Wt,
    const void* __restrict__ boff, const void* __restrict__ battn,
    const void* __restrict__ bv, int layer,
    unsigned short* __restrict__ pool, unsigned short* __restrict__ vb,
    int ytiles, const int* __restrict__ dflag)
{
    const int isb = *dflag;
    __shared__ __align__(16) unsigned short As[64 * LDSP];
    __shared__ __align__(16) unsigned short Bs[128 * LDSP];
    int byi, bxi; swz(blockIdx.x, ytiles, 5, byi, bxi);
    const int bm = byi * 64, bn = bxi * 128;
    const int isV = (bn >= 384);
    const int tid = threadIdx.x;
    const int lane = tid & 63, w = tid >> 6;
    const int quad = lane >> 4, l15 = lane & 15;
    const int wm = w & 1, wn = w >> 1;

    f32x4 acc[2][4];
    #pragma unroll
    for (int i = 0; i < 2; ++i)
        #pragma unroll
        for (int j = 0; j < 4; ++j)
            acc[i][j] = (f32x4){0.f, 0.f, 0.f, 0.f};

    const int ak4 = tid & 15, ar = tid >> 4;
    const int bk8 = tid & 7,  bnr = tid >> 3;

    for (int k0 = 0; k0 < 256; k0 += 64) {
        #pragma unroll
        for (int i = 0; i < 4; ++i) {
            int rr = ar + i * 16;
            ushort4 o = *(const ushort4*)(curb + (size_t)(bm + rr) * 256 + k0 + ak4 * 4);
            if (!isV) {
                ushort4 y = *(const ushort4*)(posb + (size_t)(bm + rr) * 256 + k0 + ak4 * 4);
                o.x = f2bfu(bfu2f(o.x) + bfu2f(y.x));
                o.y = f2bfu(bfu2f(o.y) + bfu2f(y.y));
                o.z = f2bfu(bfu2f(o.z) + bfu2f(y.z));
                o.w = f2bfu(bfu2f(o.w) + bfu2f(y.w));
            }
            *(ushort4*)(&As[rr * LDSP + ak4 * 4]) = o;
        }
        #pragma unroll
        for (int i = 0; i < 4; ++i) {
            int nn = bnr + i * 32;
            uint4 xv = *(const uint4*)((const unsigned short*)Wt +
                    (size_t)(bn + nn) * 256 + k0 + bk8 * 8);
            *(uint4*)(&Bs[nn * LDSP + bk8 * 8]) = xv;
        }
        __syncthreads();
        #pragma unroll
        for (int kk = 0; kk < 64; kk += 32) {
            short8 af[2], bf[4];
            #pragma unroll
            for (int mt = 0; mt < 2; ++mt)
                af[mt] = *(const short8*)(&As[(wm * 32 + mt * 16 + l15) * LDSP + kk + quad * 8]);
            #pragma unroll
            for (int nt = 0; nt < 4; ++nt)
                bf[nt] = *(const short8*)(&Bs[(wn * 64 + nt * 16 + l15) * LDSP + kk + quad * 8]);
            #pragma unroll
            for (int mt = 0; mt < 2; ++mt)
                #pragma unroll
                for (int nt = 0; nt < 4; ++nt)
                    acc[mt][nt] = __builtin_amdgcn_mfma_f32_16x16x32_bf16(
                        af[mt], bf[nt], acc[mt][nt], 0, 0, 0);
        }
        __syncthreads();
    }

    #pragma unroll
    for (int nt = 0; nt < 4; ++nt) {
        int gcol = bn + wn * 64 + nt * 16 + l15;
        float bvv;
        if (gcol < 256)      bvv = ldin(boff,  (size_t)layer * 256 + gcol, isb);
        else if (gcol < 384) bvv = ldin(battn, (size_t)layer * 128 + (gcol - 256), isb);
        else                 bvv = ldin(bv,    (size_t)layer * 256 + (gcol - 384), isb);
        #pragma unroll
        for (int mt = 0; mt < 2; ++mt) {
            #pragma unroll
            for (int r = 0; r < 4; ++r) {
                int grow = bm + wm * 32 + mt * 16 + quad * 4 + r;
                unsigned short ob = f2bfu(acc[mt][nt][r] + bvv);
                if (gcol < 384) pool[(size_t)grow * 384 + gcol] = ob;
                else            vb[(size_t)grow * 256 + (gcol - 384)] = ob;
            }
        }
    }
}

// ---------------------------------------------------------------------------
// gemm_ln: tile 32x256 (full row), fused bias + resid + LayerNorm epilogue.
// ---------------------------------------------------------------------------
__global__ __launch_bounds__(256) void gemm_ln(
    const unsigned short* __restrict__ A, int lda,
    const __hip_bfloat16* __restrict__ Wt,
    const void* __restrict__ bias, size_t bofs,
    const float* __restrict__ resid,
    const void* __restrict__ g, const void* __restrict__ bt, size_t lofs,
    float* __restrict__ out, __hip_bfloat16* __restrict__ outb,
    int K, const int* __restrict__ dflag)
{
    const int isb = *dflag;
    __shared__ __align__(16) unsigned short As[32 * LDSP];
    __shared__ __align__(16) unsigned short Bs[256 * LDSP];
    __shared__ float ps[4][32], pq[4][32], mrow[32], rrow[32];
    int byi, bxi; swz(blockIdx.x, gridDim.x, 1, byi, bxi);
    const int bm = byi * 32;
    const int tid = threadIdx.x;
    const int lane = tid & 63, w = tid >> 6;
    const int quad = lane >> 4, l15 = lane & 15;

    f32x4 acc[2][4];
    #pragma unroll
    for (int i = 0; i < 2; ++i)
        #pragma unroll
        for (int j = 0; j < 4; ++j)
            acc[i][j] = (f32x4){0.f, 0.f, 0.f, 0.f};

    const int ak4 = tid & 15, ar = tid >> 4;
    const int bk8 = tid & 7,  bnr = tid >> 3;

    for (int k0 = 0; k0 < K; k0 += 64) {
        #pragma unroll
        for (int i = 0; i < 2; ++i) {
            int rr = ar + i * 16;
            ushort4 o = *(const ushort4*)(A + (size_t)(bm + rr) * lda + k0 + ak4 * 4);
            *(ushort4*)(&As[rr * LDSP + ak4 * 4]) = o;
        }
        #pragma unroll
        for (int i = 0; i < 8; ++i) {
            int nn = bnr + i * 32;
            uint4 xv = *(const uint4*)((const unsigned short*)Wt +
                    (size_t)nn * K + k0 + bk8 * 8);
            *(uint4*)(&Bs[nn * LDSP + bk8 * 8]) = xv;
        }
        __syncthreads();
        #pragma unroll
        for (int kk = 0; kk < 64; kk += 32) {
            short8 af[2], bf[4];
            #pragma unroll
            for (int mt = 0; mt < 2; ++mt)
                af[mt] = *(const short8*)(&As[(mt * 16 + l15) * LDSP + kk + quad * 8]);
            #pragma unroll
            for (int nt = 0; nt < 4; ++nt)
                bf[nt] = *(const short8*)(&Bs[(w * 64 + nt * 16 + l15) * LDSP + kk + quad * 8]);
            #pragma unroll
            for (int mt = 0; mt < 2; ++mt)
                #pragma unroll
                for (int nt = 0; nt < 4; ++nt)
                    acc[mt][nt] = __builtin_amdgcn_mfma_f32_16x16x32_bf16(
                        af[mt], bf[nt], acc[mt][nt], 0, 0, 0);
        }
        __syncthreads();
    }

    float bvv[4];
    #pragma unroll
    for (int nt = 0; nt < 4; ++nt)
        bvv[nt] = ldin(bias, bofs + w * 64 + nt * 16 + l15, isb);

    #pragma unroll
    for (int mt = 0; mt < 2; ++mt) {
        #pragma unroll
        for (int r = 0; r < 4; ++r) {
            int row = mt * 16 + quad * 4 + r;
            float s = 0.f, sq = 0.f;
            #pragma unroll
            for (int nt = 0; nt < 4; ++nt) {
                int gcol = w * 64 + nt * 16 + l15;
                float v = acc[mt][nt][r] + bvv[nt] +
                          resid[(size_t)(bm + row) * 256 + gcol];
                acc[mt][nt][r] = v;
                s += v; sq += v * v;
            }
            #pragma unroll
            for (int o = 1; o < 16; o <<= 1) {
                s  += __shfl_xor(s,  o, 64);
                sq += __shfl_xor(sq, o, 64);
            }
            if (l15 == 0) { ps[w][row] = s; pq[w][row] = sq; }
        }
    }
    __syncthreads();
    if (tid < 32) {
        float s = ps[0][tid] + ps[1][tid] + ps[2][tid] + ps[3][tid];
        float sq = pq[0][tid] + pq[1][tid] + pq[2][tid] + pq[3][tid];
        float mean = s * (1.f / 256.f);
        float var = sq * (1.f / 256.f) - mean * mean;
        mrow[tid] = mean;
        rrow[tid] = rsqrtf(var + 1e-5f);
    }
    __syncthreads();

    float gv[4], gb[4];
    #pragma unroll
    for (int nt = 0; nt < 4; ++nt) {
        int gcol = w * 64 + nt * 16 + l15;
        gv[nt] = ldin(g,  lofs + gcol, isb);
        gb[nt] = ldin(bt, lofs + gcol, isb);
    }
    #pragma unroll
    for (int mt = 0; mt < 2; ++mt) {
        #pragma unroll
        for (int r = 0; r < 4; ++r) {
            int row = mt * 16 + quad * 4 + r;
            float mean = mrow[row], rstd = rrow[row];
            #pragma unroll
            for (int nt = 0; nt < 4; ++nt) {
                int gcol = w * 64 + nt * 16 + l15;
                float v = (acc[mt][nt][r] - mean) * rstd * gv[nt] + gb[nt];
                size_t di = (size_t)(bm + row) * 256 + gcol;
                out[di] = v;
                outb[di] = __float2bfloat16(v);
            }
        }
    }
}

// ---------------------------------------------------------------------------
// legacy 64x128 GEMM (chunked fallback path)
// ---------------------------------------------------------------------------
__global__ __launch_bounds__(256) void gemm_mfma64(
    const unsigned short* __restrict__ A, int lda,
    const unsigned short* __restrict__ A2,
    const __hip_bfloat16* __restrict__ Wt,
    const void* __restrict__ bias1, size_t bofs1, int n1,
    const void* __restrict__ bias2, size_t bofs2,
    void* __restrict__ C, int c_bf16, int ldc,
    int N, int K, int ytiles, int nX, const int* __restrict__ dflag)
{
    const int isb = *dflag;
    __shared__ __align__(16) unsigned short As[64 * LDSP];
    __shared__ __align__(16) unsigned short Bs[128 * LDSP];
    int byi, bxi; swz(blockIdx.x, ytiles, nX, byi, bxi);
    const int bm = byi * 64, bn = bxi * 128;
    const int tid = threadIdx.x;
    const int lane = tid & 63, w = tid >> 6;
    const int quad = lane >> 4, l15 = lane & 15;
    const int wm = w & 1, wn = w >> 1;

    f32x4 acc[2][4];
    #pragma unroll
    for (int i = 0; i < 2; ++i)
        #pragma unroll
        for (int j = 0; j < 4; ++j)
            acc[i][j] = (f32x4){0.f, 0.f, 0.f, 0.f};

    const int ak4 = tid & 15, ar = tid >> 4;
    const int bk8 = tid & 7,  bnr = tid >> 3;

    for (int k0 = 0; k0 < K; k0 += 64) {
        #pragma unroll
        for (int i = 0; i < 4; ++i) {
            int rr = ar + i * 16;
            ushort4 o = *(const ushort4*)(A + (size_t)(bm + rr) * lda + k0 + ak4 * 4);
            if (A2) {
                ushort4 y = *(const ushort4*)(A2 + (size_t)(bm + rr) * lda + k0 + ak4 * 4);
                o.x = f2bfu(bfu2f(o.x) + bfu2f(y.x));
                o.y = f2bfu(bfu2f(o.y) + bfu2f(y.y));
                o.z = f2bfu(bfu2f(o.z) + bfu2f(y.z));
                o.w = f2bfu(bfu2f(o.w) + bfu2f(y.w));
            }
            *(ushort4*)(&As[rr * LDSP + ak4 * 4]) = o;
        }
        #pragma unroll
        for (int i = 0; i < 4; ++i) {
            int nn = bnr + i * 32;
            uint4 xv = *(const uint4*)((const unsigned short*)Wt +
                    (size_t)(bn + nn) * K + k0 + bk8 * 8);
            *(uint4*)(&Bs[nn * LDSP + bk8 * 8]) = xv;
        }
        __syncthreads();
        #pragma unroll
        for (int kk = 0; kk < 64; kk += 32) {
            short8 af[2], bf[4];
            #pragma unroll
            for (int mt = 0; mt < 2; ++mt)
                af[mt] = *(const short8*)(&As[(wm * 32 + mt * 16 + l15) * LDSP + kk + quad * 8]);
            #pragma unroll
            for (int nt = 0; nt < 4; ++nt)
                bf[nt] = *(const short8*)(&Bs[(wn * 64 + nt * 16 + l15) * LDSP + kk + quad * 8]);
            #pragma unroll
            for (int mt = 0; mt < 2; ++mt)
                #pragma unroll
                for (int nt = 0; nt < 4; ++nt)
                    acc[mt][nt] = __builtin_amdgcn_mfma_f32_16x16x32_bf16(
                        af[mt], bf[nt], acc[mt][nt], 0, 0, 0);
        }
        __syncthreads();
    }

    #pragma unroll
    for (int nt = 0; nt < 4; ++nt) {
        int gcol = bn + wn * 64 + nt * 16 + l15;
        float bv = (gcol < n1) ? ldin(bias1, bofs1 + gcol, isb)
                               : ldin(bias2, bofs2 + (gcol - n1), isb);
        #pragma unroll
        for (int mt = 0; mt < 2; ++mt) {
            #pragma unroll
            for (int r = 0; r < 4; ++r) {
                int grow = bm + wm * 32 + mt * 16 + quad * 4 + r;
                float v = acc[mt][nt][r] + bv;
                if (c_bf16)
                    ((__hip_bfloat16*)C)[(size_t)grow * ldc + gcol] = __float2bfloat16(v);
                else
                    ((float*)C)[(size_t)grow * ldc + gcol] = v;
            }
        }
    }
}

// ---------------------------------------------------------------------------
// deformable attention: one WAVE per row, 4 rows per block.
// cn layout [rl][j][h][c] int2 — gather reads are 2x ds_read_b128 per j,
// bank-pattern h*8%32 (2-way alias = free, dg-lanes broadcast). Phase-1
// writes are 8-way conflicted but only 4 instrs/lane.
// ---------------------------------------------------------------------------
__global__ __launch_bounds__(256) void deform_kernel(
    const __hip_bfloat16* __restrict__ v,
    __hip_bfloat16* __restrict__ oa,
    int row0)
{
    __shared__ float sw[4][128];
    __shared__ __align__(16) int2 cn[4][16][8][4];   // [row][j][h][corner] {addr, wgt}

    const int tid = threadIdx.x;
    const int rl = tid >> 6, lane = tid & 63;
    const int lrow = blockIdx.x * 4 + rl;
    const int row = lrow + row0;
    const int b = row / LQ_, q = row % LQ_;
    int lq, qy, qx; decode_q(q, lq, qy, qx);
    const size_t obase = (size_t)lrow * 384;
    const float sizes[4] = {64.f, 32.f, 16.f, 8.f};
    const int   dims[4]  = {64, 32, 16, 8};
    const int   starts[4] = {0, 4096, 5120, 5376};
    const float refx = (qx + 0.5f) / sizes[lq];
    const float refy = (qy + 0.5f) / sizes[lq];

    if (lane < 8) {
        float lg[16], mx = -1e30f;
        #pragma unroll
        for (int j = 0; j < 16; ++j) {
            lg[j] = __bfloat162float(oa[obase + 256 + lane * 16 + j]);
            mx = fmaxf(mx, lg[j]);
        }
        float s = 0.f;
        #pragma unroll
        for (int j = 0; j < 16; ++j) { lg[j] = __expf(lg[j] - mx); s += lg[j]; }
        float inv = 1.f / s;
        #pragma unroll
        for (int j = 0; j < 16; ++j) sw[rl][lane * 16 + j] = lg[j] * inv;
    }
    __syncthreads();

    #pragma unroll
    for (int t = 0; t < 2; ++t) {
        int s = lane * 2 + t;         // h*16 + j
        int h = s >> 4, j = s & 15, l = j >> 2;
        int Wl = dims[l], st = starts[l];
        float siz = sizes[l];
        float ox = __bfloat162float(oa[obase + h * 32 + j * 2 + 0]);
        float oy = __bfloat162float(oa[obase + h * 32 + j * 2 + 1]);
        float x = refx * siz + ox - 0.5f;
        float y = refy * siz + oy - 0.5f;
        float x0f = floorf(x), y0f = floorf(y);
        int x0 = (int)x0f, y0 = (int)y0f;
        float wx = x - x0f, wy = y - y0f;
        float wq = sw[rl][s];
        int vbase = b * LQ_ + st;
        int2 tmp[4];
        #pragma unroll
        for (int c = 0; c < 4; ++c) {
            int cy = c >> 1, cx = c & 1;
            int yi = y0 + cy, xi = x0 + cx;
            float valid = (yi >= 0 && yi < Wl && xi >= 0 && xi < Wl) ? 1.f : 0.f;
            int yc = min(max(yi, 0), Wl - 1);
            int xc = min(max(xi, 0), Wl - 1);
            float cw = (cy ? wy : 1.f - wy) * (cx ? wx : 1.f - wx);
            float wgt = wq * cw * valid;
            int addr = (vbase + yc * Wl + xc) * 256 + h * 32;
            tmp[c] = make_int2(addr, __float_as_int(wgt));
        }
        *(int4*)&cn[rl][j][h][0] = *(int4*)&tmp[0];
        *(int4*)&cn[rl][j][h][2] = *(int4*)&tmp[2];
    }
    __syncthreads();

    {
        const int h = lane >> 3, dg = lane & 7;
        const unsigned short* vp = (const unsigned short*)v;
        float a0 = 0.f, a1 = 0.f, a2 = 0.f, a3 = 0.f;
        #pragma unroll 4
        for (int j = 0; j < 16; ++j) {
            int2 c4[4];
            *(int4*)&c4[0] = *(const int4*)&cn[rl][j][h][0];
            *(int4*)&c4[2] = *(const int4*)&cn[rl][j][h][2];
            #pragma unroll
            for (int c = 0; c < 4; ++c) {
                float wgt = __int_as_float(c4[c].y);
                uint2 u = *(const uint2*)(vp + c4[c].x + dg * 4);
                float f0 = __uint_as_float(u.x << 16);
                float f1 = __uint_as_float(u.x & 0xffff0000u);
                float f2 = __uint_as_float(u.y << 16);
                float f3 = __uint_as_float(u.y & 0xffff0000u);
                a0 += wgt * f0; a1 += wgt * f1; a2 += wgt * f2; a3 += wgt * f3;
            }
        }
        ushort4 o;
        o.x = f2bfu(a0); o.y = f2bfu(a1); o.z = f2bfu(a2); o.w = f2bfu(a3);
        *(ushort4*)((unsigned short*)oa + obase + h * 32 + dg * 4) = o;
    }
}

// cast/copy to output
__global__ __launch_bounds__(256) void cast_kernel(
    const float* __restrict__ x, const unsigned short* __restrict__ xb,
    void* __restrict__ out, const int* __restrict__ dflag)
{
    size_t i = (size_t)blockIdx.x * 256 + threadIdx.x;
    if (*dflag) ((unsigned short*)out)[i] = xb[i];
    else        ((float*)out)[i] = x[i];
}

// ---------------------------------------------------------------------------
extern "C" void kernel_launch(void* const* d_in, const int* in_sizes, int n_in,
                              void* d_out, int out_size, void* d_ws, size_t ws_size,
                              hipStream_t stream)
{
    const void* s0 = d_in[0];  const void* p0 = d_in[1];
    const void* s1 = d_in[2];  const void* p1 = d_in[3];
    const void* s2 = d_in[4];  const void* p2 = d_in[5];
    const void* s3 = d_in[6];  const void* p3 = d_in[7];
    const void* lvl   = d_in[8];
    const void* Woff  = d_in[9];   const void* boff  = d_in[10];
    const void* Wattn = d_in[11];  const void* battn = d_in[12];
    const void* Wv    = d_in[13];  const void* bv    = d_in[14];
    const void* Wo    = d_in[15];  const void* bo    = d_in[16];
    const void* ln1g  = d_in[17];  const void* ln1b  = d_in[18];
    const void* Wfc1  = d_in[19];  const void* bfc1  = d_in[20];
    const void* Wfc2  = d_in[21];  const void* bfc2  = d_in[22];
    const void* ln2g  = d_in[23];  const void* ln2b  = d_in[24];

    // ---- workspace layout (bytes) ----
    char* base = (char*)d_ws;
    size_t off = 0;
    int* dflag = (int*)base;                 off += 256;
    float* cur = (float*)(base + off);       off += (size_t)M_ * 256 * 4;
    __hip_bfloat16* curb = (__hip_bfloat16*)(base + off); off += (size_t)M_ * 256 * 2;
    __hip_bfloat16* posb = (__hip_bfloat16*)(base + off); off += (size_t)M_ * 256 * 2;
    float* out1 = (float*)(base + off);      off += (size_t)M_ * 256 * 4;
    __hip_bfloat16* out1b = (__hip_bfloat16*)(base + off); off += (size_t)M_ * 256 * 2;
    __hip_bfloat16* Wt = (__hip_bfloat16*)(base + off);   off += (size_t)WL_ * NL_ * 2;
    off = (off + 255) & ~(size_t)255;
    __hip_bfloat16* vb = (__hip_bfloat16*)(base + off);
    size_t vbOff = off;                      off += (size_t)M_ * 256 * 2;
    off = (off + 255) & ~(size_t)255;
    __hip_bfloat16* pool = (__hip_bfloat16*)(base + off);
    size_t poolBytes   = (ws_size > off) ? ws_size - off : 0;
    size_t phase2Bytes = (ws_size > vbOff) ? ws_size - vbOff : 0;
    __hip_bfloat16* hid = vb;

    const int NCopt[8] = {1, 2, 5, 10, 17, 34, 85, 170};
    int NCd = 170, NCf = 170;
    for (int t = 0; t < 8; ++t)
        if ((size_t)(M_ / NCopt[t]) * 768 <= poolBytes) { NCd = NCopt[t]; break; }
    for (int t = 0; t < 8; ++t)
        if ((size_t)(M_ / NCopt[t]) * 2048 <= phase2Bytes) { NCf = NCopt[t]; break; }
    const int CHd = M_ / NCd, CHf = M_ / NCf;

    detect_kernel<<<1, 1, 0, stream>>>((const unsigned int*)ln1g, dflag);

    transpose_kernel<<<dim3(12, 8, NL_), 256, 0, stream>>>(
        Woff, 256 * 256, 256, Wattn, 256 * 128, 128, 256, Wt, WOFS_OAV, dflag);
    transpose_kernel<<<dim3(8, 8, NL_), 256, 0, stream>>>(
        Wv, 256 * 256, 256, nullptr, 0, 0, 256, Wt, WOFS_V, dflag);
    transpose_kernel<<<dim3(8, 8, NL_), 256, 0, stream>>>(
        Wo, 256 * 256, 256, nullptr, 0, 0, 256, Wt, WOFS_O, dflag);
    transpose_kernel<<<dim3(32, 8, NL_), 256, 0, stream>>>(
        Wfc1, 256 * 1024, 1024, nullptr, 0, 0, 256, Wt, WOFS_F1, dflag);
    transpose_kernel<<<dim3(8, 32, NL_), 256, 0, stream>>>(
        Wfc2, 1024 * 256, 256, nullptr, 0, 0, 1024, Wt, WOFS_F2, dflag);

    init_kernel<<<340, 256, 0, stream>>>(s0, s1, s2, s3, p0, p1, p2, p3, lvl,
                                         cur, curb, posb, dflag);

    for (int i = 0; i < NL_; ++i) {
        const __hip_bfloat16* WtL = Wt + (size_t)i * WL_;

        if (NCd == 1) {
            gemm_oav<<<5 * (M_ / 64), 256, 0, stream>>>(
                (const unsigned short*)curb, (const unsigned short*)posb,
                WtL + WOFS_OAV, boff, battn, bv, i,
                (unsigned short*)pool, (unsigned short*)vb, M_ / 64, dflag);
            deform_kernel<<<M_ / 4, 256, 0, stream>>>(vb, pool, 0);
            gemm_ln<<<M_ / 32, 256, 0, stream>>>(
                (const unsigned short*)pool, 384, WtL + WOFS_O,
                bo, (size_t)i * 256, cur, ln1g, ln1b, (size_t)i * 256,
                out1, out1b, 256, dflag);
        } else {
            gemm_mfma64<<<2 * (M_ / 64), 256, 0, stream>>>(
                (const unsigned short*)curb, 256, nullptr, WtL + WOFS_V,
                bv, (size_t)i * 256, 256, nullptr, 0,
                vb, 1, 256, 256, 256, M_ / 64, 2, dflag);
            for (int c = 0; c < NCd; ++c) {
                size_t r0 = (size_t)c * CHd;
                gemm_mfma64<<<3 * (CHd / 64), 256, 0, stream>>>(
                    (const unsigned short*)curb + r0 * 256, 256,
                    (const unsigned short*)posb + r0 * 256, WtL + WOFS_OAV,
                    boff, (size_t)i * 256, 256, battn, (size_t)i * 128,
                    pool, 1, 384, 384, 256, CHd / 64, 3, dflag);
                deform_kernel<<<CHd / 4, 256, 0, stream>>>(vb, pool, (int)r0);
                gemm_ln<<<CHd / 32, 256, 0, stream>>>(
                    (const unsigned short*)pool, 384, WtL + WOFS_O,
                    bo, (size_t)i * 256, cur + r0 * 256, ln1g, ln1b, (size_t)i * 256,
                    out1 + r0 * 256, out1b + r0 * 256, 256, dflag);
            }
        }

        for (int c = 0; c < NCf; ++c) {
            size_t r0 = (size_t)c * CHf;
            gemm_mfma<<<8 * (CHf / 128), 256, 0, stream>>>(
                (const unsigned short*)out1b + r0 * 256, 256, WtL + WOFS_F1,
                bfc1, (size_t)i * 1024, hid, 1, 1024, 1024, 256, 1,
                CHf / 128, 8, dflag);
            gemm_ln<<<CHf / 32, 256, 0, stream>>>(
                (const unsigned short*)hid, 1024, WtL + WOFS_F2,
                bfc2, (size_t)i * 256, out1 + r0 * 256, ln2g, ln2b, (size_t)i * 256,
                cur + r0 * 256, curb + r0 * 256, 1024, dflag);
        }
    }

    cast_kernel<<<(M_ * 256) / 256, 256, 0, stream>>>(
        cur, (const unsigned short*)curb, d_out, dflag);
}

// Round 9
// 1125.721 us; speedup vs baseline: 1.0103x; 1.0103x over previous
//
#include <hip/hip_runtime.h>
#include <hip/hip_bf16.h>
#include <string.h>

// Problem constants
#define B_ 4
#define D_ 256
#define H_ 8
#define HD_ 32
#define L_ 4
#define P_ 4
#define NL_ 6
#define FF_ 1024
#define LQ_ 5440
#define M_ (B_ * LQ_)   // 21760 = 170*128 = 340*64 = 680*32

typedef __attribute__((ext_vector_type(8))) short short8;
typedef __attribute__((ext_vector_type(4))) float f32x4;

// per-layer transposed-weight block (bf16), [N][K] k-contig:
//   OAV (640 x 256)  ofs 0      (0-255 Woff, 256-383 Wattn, 384-639 Wv)
//   O   (256 x 256)  ofs 163840
//   FC1 (1024 x 256) ofs 229376
//   FC2 (256 x 1024) ofs 491520
#define WL_ 753664
#define WOFS_OAV 0
#define WOFS_V   98304   // = 384*256, V sub-block inside OAV
#define WOFS_O   163840
#define WOFS_F1  229376
#define WOFS_F2  491520

// ---------------------------------------------------------------------------
__device__ __forceinline__ float ldin(const void* p, size_t i, int isb) {
    if (isb) return __bfloat162float(((const __hip_bfloat16*)p)[i]);
    return ((const float*)p)[i];
}
__device__ __forceinline__ float bfu2f(unsigned short u) {
    __hip_bfloat16 h; memcpy(&h, &u, 2); return __bfloat162float(h);
}
__device__ __forceinline__ unsigned short f2bfu(float f) {
    __hip_bfloat16 h = __float2bfloat16(f);
    unsigned short u; memcpy(&u, &h, 2); return u;
}

__global__ void detect_kernel(const unsigned int* __restrict__ g, int* __restrict__ flag) {
    *flag = (g[0] == 0x3F800000u) ? 0 : 1;
}

// level tables: shapes (64,64),(32,32),(16,16),(8,8); starts 0,4096,5120,5376
__device__ __forceinline__ void decode_q(int q, int& l, int& y, int& x) {
    if (q < 4096)      { l = 0; y = q >> 6; x = q & 63; }
    else if (q < 5120) { q -= 4096; l = 1; y = q >> 5; x = q & 31; }
    else if (q < 5376) { q -= 5120; l = 2; y = q >> 4; x = q & 15; }
    else               { q -= 5376; l = 3; y = q >> 3; x = q & 7;  }
}

// supertile swizzle (XCD L2 locality): groups of 8 m-stripes x all n-tiles.
__device__ __forceinline__ void swz(int flat, int ytiles, int nX, int& by, int& bx) {
    int sgsize = 8 * nX;
    int sg = flat / sgsize, rem = flat % sgsize;
    int h8 = ytiles - sg * 8; if (h8 > 8) h8 = 8;
    by = sg * 8 + rem % h8;
    bx = rem / h8;
}

// ---------------------------------------------------------------------------
// weight transpose: W[K][N1]+W[K][N2] (concat cols) -> dst[n][k] bf16
// ---------------------------------------------------------------------------
__global__ __launch_bounds__(256) void transpose_kernel(
    const void* __restrict__ W1, int w1ls, int N1,
    const void* __restrict__ W2, int w2ls, int N2,
    int K, __hip_bfloat16* __restrict__ dst, int dofs,
    const int* __restrict__ dflag)
{
    const int isb = *dflag;
    const int layer = blockIdx.z;
    const int bn = blockIdx.x * 32, bk = blockIdx.y * 32;
    const int t = threadIdx.x;
    __shared__ unsigned short tile[32][33];
    const int nl = t & 31;
    #pragma unroll
    for (int i = 0; i < 4; ++i) {
        int kl = (t >> 5) + i * 8;
        int n = bn + nl, k = bk + kl;
        float v;
        if (n < N1) v = ldin(W1, (size_t)layer * w1ls + (size_t)k * N1 + n, isb);
        else        v = ldin(W2, (size_t)layer * w2ls + (size_t)k * N2 + (n - N1), isb);
        tile[kl][nl] = f2bfu(v);
    }
    __syncthreads();
    #pragma unroll
    for (int i = 0; i < 4; ++i) {
        int nl2 = (t >> 5) + i * 8;
        int n = bn + nl2, k = bk + (t & 31);
        unsigned short u = tile[t & 31][nl2];
        memcpy(&dst[(size_t)layer * WL_ + dofs + (size_t)n * K + k], &u, 2);
    }
}

// ---------------------------------------------------------------------------
// init v3: block = 64 pixels x 256 ch of one level, vectorized both sides.
// ---------------------------------------------------------------------------
__global__ __launch_bounds__(256) void init_kernel(
    const void* __restrict__ s0, const void* __restrict__ s1,
    const void* __restrict__ s2, const void* __restrict__ s3,
    const void* __restrict__ p0, const void* __restrict__ p1,
    const void* __restrict__ p2, const void* __restrict__ p3,
    const void* __restrict__ lvl_emb,
    float* __restrict__ cur, __hip_bfloat16* __restrict__ curb,
    __hip_bfloat16* __restrict__ posb,
    const int* __restrict__ dflag)
{
    const int isb = *dflag;
    const int tid = threadIdx.x;
    int blk = blockIdx.x;            // 0..339
    int b = blk / 85, t = blk % 85;
    int l, pix0, HW, start;
    if (t < 64)      { l = 0; pix0 = t * 64;        HW = 4096; start = 0; }
    else if (t < 80) { l = 1; pix0 = (t - 64) * 64; HW = 1024; start = 4096; }
    else if (t < 84) { l = 2; pix0 = (t - 80) * 64; HW = 256;  start = 5120; }
    else             { l = 3; pix0 = 0;             HW = 64;   start = 5376; }
    const void* sp = (l == 0) ? s0 : (l == 1) ? s1 : (l == 2) ? s2 : s3;
    const void* pp = (l == 0) ? p0 : (l == 1) ? p1 : (l == 2) ? p2 : p3;
    const int rowbase = b * LQ_ + start + pix0;

    __shared__ float tile[32][68];
    #pragma unroll
    for (int pass = 0; pass < 2; ++pass) {
        const void* gp = pass ? pp : sp;
        for (int ct = 0; ct < 8; ++ct) {
            __syncthreads();
            {   // read 32ch x 64pix (float4/ushort4 along pixels)
                int pl4 = (tid & 15) * 4;
                #pragma unroll
                for (int s = 0; s < 2; ++s) {
                    int cl = (tid >> 4) + s * 16;
                    size_t gi = ((size_t)b * 256 + ct * 32 + cl) * (size_t)HW + pix0 + pl4;
                    float4 v;
                    if (isb) {
                        ushort4 u = *(const ushort4*)((const unsigned short*)gp + gi);
                        v.x = bfu2f(u.x); v.y = bfu2f(u.y); v.z = bfu2f(u.z); v.w = bfu2f(u.w);
                    } else {
                        v = *(const float4*)((const float*)gp + gi);
                    }
                    tile[cl][pl4 + 0] = v.x; tile[cl][pl4 + 1] = v.y;
                    tile[cl][pl4 + 2] = v.z; tile[cl][pl4 + 3] = v.w;
                }
            }
            __syncthreads();
            {   // write: 32 pix-rows x 8 ch-quads (float4/ushort4 along ch)
                int cq = tid & 7, c4 = ct * 32 + cq * 4;
                #pragma unroll
                for (int s = 0; s < 2; ++s) {
                    int prow = (tid >> 3) + s * 32;
                    float4 ov;
                    ov.x = tile[cq * 4 + 0][prow]; ov.y = tile[cq * 4 + 1][prow];
                    ov.z = tile[cq * 4 + 2][prow]; ov.w = tile[cq * 4 + 3][prow];
                    size_t di = (size_t)(rowbase + prow) * 256 + c4;
                    if (pass == 0) {
                        *(float4*)(cur + di) = ov;
                        ushort4 ob;
                        ob.x = f2bfu(ov.x); ob.y = f2bfu(ov.y);
                        ob.z = f2bfu(ov.z); ob.w = f2bfu(ov.w);
                        *(ushort4*)((unsigned short*)curb + di) = ob;
                    } else {
                        ushort4 ob;
                        ob.x = f2bfu(ov.x + ldin(lvl_emb, l * 256 + c4 + 0, isb));
                        ob.y = f2bfu(ov.y + ldin(lvl_emb, l * 256 + c4 + 1, isb));
                        ob.z = f2bfu(ov.z + ldin(lvl_emb, l * 256 + c4 + 2, isb));
                        ob.w = f2bfu(ov.w + ldin(lvl_emb, l * 256 + c4 + 3, isb));
                        *(ushort4*)((unsigned short*)posb + di) = ob;
                    }
                }
            }
        }
    }
}

// ---------------------------------------------------------------------------
// MFMA GEMM 128x128 (fc1): BK=64, 4 waves (2x2), wave 64x64. A bf16.
// ---------------------------------------------------------------------------
#define LDSP 72
__global__ __launch_bounds__(256) void gemm_mfma(
    const unsigned short* __restrict__ A, int lda,
    const __hip_bfloat16* __restrict__ Wt,
    const void* __restrict__ bias, size_t bofs,
    void* __restrict__ C, int c_bf16, int ldc,
    int N, int K, int relu, int ytiles, int nX, const int* __restrict__ dflag)
{
    const int isb = *dflag;
    __shared__ __align__(16) unsigned short As[128 * LDSP];
    __shared__ __align__(16) unsigned short Bs[128 * LDSP];
    int byi, bxi; swz(blockIdx.x, ytiles, nX, byi, bxi);
    const int bm = byi * 128, bn = bxi * 128;
    const int tid = threadIdx.x;
    const int lane = tid & 63, w = tid >> 6;
    const int quad = lane >> 4, l15 = lane & 15;
    const int wm = w & 1, wn = w >> 1;

    f32x4 acc[4][4];
    #pragma unroll
    for (int i = 0; i < 4; ++i)
        #pragma unroll
        for (int j = 0; j < 4; ++j)
            acc[i][j] = (f32x4){0.f, 0.f, 0.f, 0.f};

    const int ak4 = tid & 15, ar = tid >> 4;
    const int bk8 = tid & 7,  bnr = tid >> 3;

    for (int k0 = 0; k0 < K; k0 += 64) {
        #pragma unroll
        for (int i = 0; i < 8; ++i) {
            int rr = ar + i * 16;
            ushort4 o = *(const ushort4*)(A + (size_t)(bm + rr) * lda + k0 + ak4 * 4);
            *(ushort4*)(&As[rr * LDSP + ak4 * 4]) = o;
        }
        #pragma unroll
        for (int i = 0; i < 4; ++i) {
            int nn = bnr + i * 32;
            uint4 xv = *(const uint4*)((const unsigned short*)Wt +
                    (size_t)(bn + nn) * K + k0 + bk8 * 8);
            *(uint4*)(&Bs[nn * LDSP + bk8 * 8]) = xv;
        }
        __syncthreads();
        #pragma unroll
        for (int kk = 0; kk < 64; kk += 32) {
            short8 af[4], bf[4];
            #pragma unroll
            for (int mt = 0; mt < 4; ++mt)
                af[mt] = *(const short8*)(&As[(wm * 64 + mt * 16 + l15) * LDSP + kk + quad * 8]);
            #pragma unroll
            for (int nt = 0; nt < 4; ++nt)
                bf[nt] = *(const short8*)(&Bs[(wn * 64 + nt * 16 + l15) * LDSP + kk + quad * 8]);
            #pragma unroll
            for (int mt = 0; mt < 4; ++mt)
                #pragma unroll
                for (int nt = 0; nt < 4; ++nt)
                    acc[mt][nt] = __builtin_amdgcn_mfma_f32_16x16x32_bf16(
                        af[mt], bf[nt], acc[mt][nt], 0, 0, 0);
        }
        __syncthreads();
    }

    #pragma unroll
    for (int nt = 0; nt < 4; ++nt) {
        int gcol = bn + wn * 64 + nt * 16 + l15;
        float bv = ldin(bias, bofs + gcol, isb);
        #pragma unroll
        for (int mt = 0; mt < 4; ++mt) {
            #pragma unroll
            for (int r = 0; r < 4; ++r) {
                int grow = bm + wm * 64 + mt * 16 + quad * 4 + r;
                float v = acc[mt][nt][r] + bv;
                if (relu) v = fmaxf(v, 0.f);
                if (c_bf16)
                    ((__hip_bfloat16*)C)[(size_t)grow * ldc + gcol] = __float2bfloat16(v);
                else
                    ((float*)C)[(size_t)grow * ldc + gcol] = v;
            }
        }
    }
}

// ---------------------------------------------------------------------------
// gemm_oav: tile 64x128 over N=640. cols 0-383: A=curb+posb, [Woff|Wattn];
// cols 384-639: A=curb, Wv. C split: pool [M,384] bf16 / vb [M,256] bf16.
// ---------------------------------------------------------------------------
__global__ __launch_bounds__(256) void gemm_oav(
    const unsigned short* __restrict__ curb,
    const unsigned short* __restrict__ posb,
    const __hip_bfloat16* __restrict__ Wt,
    const void* __restrict__ boff, const void* __restrict__ battn,
    const void* __restrict__ bv, int layer,
    unsigned short* __restrict__ pool, unsigned short* __restrict__ vb,
    int ytiles, const int* __restrict__ dflag)
{
    const int isb = *dflag;
    __shared__ __align__(16) unsigned short As[64 * LDSP];
    __shared__ __align__(16) unsigned short Bs[128 * LDSP];
    int byi, bxi; swz(blockIdx.x, ytiles, 5, byi, bxi);
    const int bm = byi * 64, bn = bxi * 128;
    const int isV = (bn >= 384);
    const int tid = threadIdx.x;
    const int lane = tid & 63, w = tid >> 6;
    const int quad = lane >> 4, l15 = lane & 15;
    const int wm = w & 1, wn = w >> 1;

    f32x4 acc[2][4];
    #pragma unroll
    for (int i = 0; i < 2; ++i)
        #pragma unroll
        for (int j = 0; j < 4; ++j)
            acc[i][j] = (f32x4){0.f, 0.f, 0.f, 0.f};

    const int ak4 = tid & 15, ar = tid >> 4;
    const int bk8 = tid & 7,  bnr = tid >> 3;

    for (int k0 = 0; k0 < 256; k0 += 64) {
        #pragma unroll
        for (int i = 0; i < 4; ++i) {
            int rr = ar + i * 16;
            ushort4 o = *(const ushort4*)(curb + (size_t)(bm + rr) * 256 + k0 + ak4 * 4);
            if (!isV) {
                ushort4 y = *(const ushort4*)(posb + (size_t)(bm + rr) * 256 + k0 + ak4 * 4);
                o.x = f2bfu(bfu2f(o.x) + bfu2f(y.x));
                o.y = f2bfu(bfu2f(o.y) + bfu2f(y.y));
                o.z = f2bfu(bfu2f(o.z) + bfu2f(y.z));
                o.w = f2bfu(bfu2f(o.w) + bfu2f(y.w));
            }
            *(ushort4*)(&As[rr * LDSP + ak4 * 4]) = o;
        }
        #pragma unroll
        for (int i = 0; i < 4; ++i) {
            int nn = bnr + i * 32;
            uint4 xv = *(const uint4*)((const unsigned short*)Wt +
                    (size_t)(bn + nn) * 256 + k0 + bk8 * 8);
            *(uint4*)(&Bs[nn * LDSP + bk8 * 8]) = xv;
        }
        __syncthreads();
        #pragma unroll
        for (int kk = 0; kk < 64; kk += 32) {
            short8 af[2], bf[4];
            #pragma unroll
            for (int mt = 0; mt < 2; ++mt)
                af[mt] = *(const short8*)(&As[(wm * 32 + mt * 16 + l15) * LDSP + kk + quad * 8]);
            #pragma unroll
            for (int nt = 0; nt < 4; ++nt)
                bf[nt] = *(const short8*)(&Bs[(wn * 64 + nt * 16 + l15) * LDSP + kk + quad * 8]);
            #pragma unroll
            for (int mt = 0; mt < 2; ++mt)
                #pragma unroll
                for (int nt = 0; nt < 4; ++nt)
                    acc[mt][nt] = __builtin_amdgcn_mfma_f32_16x16x32_bf16(
                        af[mt], bf[nt], acc[mt][nt], 0, 0, 0);
        }
        __syncthreads();
    }

    #pragma unroll
    for (int nt = 0; nt < 4; ++nt) {
        int gcol = bn + wn * 64 + nt * 16 + l15;
        float bvv;
        if (gcol < 256)      bvv = ldin(boff,  (size_t)layer * 256 + gcol, isb);
        else if (gcol < 384) bvv = ldin(battn, (size_t)layer * 128 + (gcol - 256), isb);
        else                 bvv = ldin(bv,    (size_t)layer * 256 + (gcol - 384), isb);
        #pragma unroll
        for (int mt = 0; mt < 2; ++mt) {
            #pragma unroll
            for (int r = 0; r < 4; ++r) {
                int grow = bm + wm * 32 + mt * 16 + quad * 4 + r;
                unsigned short ob = f2bfu(acc[mt][nt][r] + bvv);
                if (gcol < 384) pool[(size_t)grow * 384 + gcol] = ob;
                else            vb[(size_t)grow * 256 + (gcol - 384)] = ob;
            }
        }
    }
}

// ---------------------------------------------------------------------------
// gemm_ln: tile 32x256 (full row), fused bias + resid + LayerNorm epilogue.
// ---------------------------------------------------------------------------
__global__ __launch_bounds__(256) void gemm_ln(
    const unsigned short* __restrict__ A, int lda,
    const __hip_bfloat16* __restrict__ Wt,
    const void* __restrict__ bias, size_t bofs,
    const float* __restrict__ resid,
    const void* __restrict__ g, const void* __restrict__ bt, size_t lofs,
    float* __restrict__ out, __hip_bfloat16* __restrict__ outb,
    int K, const int* __restrict__ dflag)
{
    const int isb = *dflag;
    __shared__ __align__(16) unsigned short As[32 * LDSP];
    __shared__ __align__(16) unsigned short Bs[256 * LDSP];
    __shared__ float ps[4][32], pq[4][32], mrow[32], rrow[32];
    int byi, bxi; swz(blockIdx.x, gridDim.x, 1, byi, bxi);
    const int bm = byi * 32;
    const int tid = threadIdx.x;
    const int lane = tid & 63, w = tid >> 6;
    const int quad = lane >> 4, l15 = lane & 15;

    f32x4 acc[2][4];
    #pragma unroll
    for (int i = 0; i < 2; ++i)
        #pragma unroll
        for (int j = 0; j < 4; ++j)
            acc[i][j] = (f32x4){0.f, 0.f, 0.f, 0.f};

    const int ak4 = tid & 15, ar = tid >> 4;
    const int bk8 = tid & 7,  bnr = tid >> 3;

    for (int k0 = 0; k0 < K; k0 += 64) {
        #pragma unroll
        for (int i = 0; i < 2; ++i) {
            int rr = ar + i * 16;
            ushort4 o = *(const ushort4*)(A + (size_t)(bm + rr) * lda + k0 + ak4 * 4);
            *(ushort4*)(&As[rr * LDSP + ak4 * 4]) = o;
        }
        #pragma unroll
        for (int i = 0; i < 8; ++i) {
            int nn = bnr + i * 32;
            uint4 xv = *(const uint4*)((const unsigned short*)Wt +
                    (size_t)nn * K + k0 + bk8 * 8);
            *(uint4*)(&Bs[nn * LDSP + bk8 * 8]) = xv;
        }
        __syncthreads();
        #pragma unroll
        for (int kk = 0; kk < 64; kk += 32) {
            short8 af[2], bf[4];
            #pragma unroll
            for (int mt = 0; mt < 2; ++mt)
                af[mt] = *(const short8*)(&As[(mt * 16 + l15) * LDSP + kk + quad * 8]);
            #pragma unroll
            for (int nt = 0; nt < 4; ++nt)
                bf[nt] = *(const short8*)(&Bs[(w * 64 + nt * 16 + l15) * LDSP + kk + quad * 8]);
            #pragma unroll
            for (int mt = 0; mt < 2; ++mt)
                #pragma unroll
                for (int nt = 0; nt < 4; ++nt)
                    acc[mt][nt] = __builtin_amdgcn_mfma_f32_16x16x32_bf16(
                        af[mt], bf[nt], acc[mt][nt], 0, 0, 0);
        }
        __syncthreads();
    }

    float bvv[4];
    #pragma unroll
    for (int nt = 0; nt < 4; ++nt)
        bvv[nt] = ldin(bias, bofs + w * 64 + nt * 16 + l15, isb);

    #pragma unroll
    for (int mt = 0; mt < 2; ++mt) {
        #pragma unroll
        for (int r = 0; r < 4; ++r) {
            int row = mt * 16 + quad * 4 + r;
            float s = 0.f, sq = 0.f;
            #pragma unroll
            for (int nt = 0; nt < 4; ++nt) {
                int gcol = w * 64 + nt * 16 + l15;
                float v = acc[mt][nt][r] + bvv[nt] +
                          resid[(size_t)(bm + row) * 256 + gcol];
                acc[mt][nt][r] = v;
                s += v; sq += v * v;
            }
            #pragma unroll
            for (int o = 1; o < 16; o <<= 1) {
                s  += __shfl_xor(s,  o, 64);
                sq += __shfl_xor(sq, o, 64);
            }
            if (l15 == 0) { ps[w][row] = s; pq[w][row] = sq; }
        }
    }
    __syncthreads();
    if (tid < 32) {
        float s = ps[0][tid] + ps[1][tid] + ps[2][tid] + ps[3][tid];
        float sq = pq[0][tid] + pq[1][tid] + pq[2][tid] + pq[3][tid];
        float mean = s * (1.f / 256.f);
        float var = sq * (1.f / 256.f) - mean * mean;
        mrow[tid] = mean;
        rrow[tid] = rsqrtf(var + 1e-5f);
    }
    __syncthreads();

    float gv[4], gb[4];
    #pragma unroll
    for (int nt = 0; nt < 4; ++nt) {
        int gcol = w * 64 + nt * 16 + l15;
        gv[nt] = ldin(g,  lofs + gcol, isb);
        gb[nt] = ldin(bt, lofs + gcol, isb);
    }
    #pragma unroll
    for (int mt = 0; mt < 2; ++mt) {
        #pragma unroll
        for (int r = 0; r < 4; ++r) {
            int row = mt * 16 + quad * 4 + r;
            float mean = mrow[row], rstd = rrow[row];
            #pragma unroll
            for (int nt = 0; nt < 4; ++nt) {
                int gcol = w * 64 + nt * 16 + l15;
                float v = (acc[mt][nt][r] - mean) * rstd * gv[nt] + gb[nt];
                size_t di = (size_t)(bm + row) * 256 + gcol;
                out[di] = v;
                outb[di] = __float2bfloat16(v);
            }
        }
    }
}

// ---------------------------------------------------------------------------
// legacy 64x128 GEMM (chunked fallback path)
// ---------------------------------------------------------------------------
__global__ __launch_bounds__(256) void gemm_mfma64(
    const unsigned short* __restrict__ A, int lda,
    const unsigned short* __restrict__ A2,
    const __hip_bfloat16* __restrict__ Wt,
    const void* __restrict__ bias1, size_t bofs1, int n1,
    const void* __restrict__ bias2, size_t bofs2,
    void* __restrict__ C, int c_bf16, int ldc,
    int N, int K, int ytiles, int nX, const int* __restrict__ dflag)
{
    const int isb = *dflag;
    __shared__ __align__(16) unsigned short As[64 * LDSP];
    __shared__ __align__(16) unsigned short Bs[128 * LDSP];
    int byi, bxi; swz(blockIdx.x, ytiles, nX, byi, bxi);
    const int bm = byi * 64, bn = bxi * 128;
    const int tid = threadIdx.x;
    const int lane = tid & 63, w = tid >> 6;
    const int quad = lane >> 4, l15 = lane & 15;
    const int wm = w & 1, wn = w >> 1;

    f32x4 acc[2][4];
    #pragma unroll
    for (int i = 0; i < 2; ++i)
        #pragma unroll
        for (int j = 0; j < 4; ++j)
            acc[i][j] = (f32x4){0.f, 0.f, 0.f, 0.f};

    const int ak4 = tid & 15, ar = tid >> 4;
    const int bk8 = tid & 7,  bnr = tid >> 3;

    for (int k0 = 0; k0 < K; k0 += 64) {
        #pragma unroll
        for (int i = 0; i < 4; ++i) {
            int rr = ar + i * 16;
            ushort4 o = *(const ushort4*)(A + (size_t)(bm + rr) * lda + k0 + ak4 * 4);
            if (A2) {
                ushort4 y = *(const ushort4*)(A2 + (size_t)(bm + rr) * lda + k0 + ak4 * 4);
                o.x = f2bfu(bfu2f(o.x) + bfu2f(y.x));
                o.y = f2bfu(bfu2f(o.y) + bfu2f(y.y));
                o.z = f2bfu(bfu2f(o.z) + bfu2f(y.z));
                o.w = f2bfu(bfu2f(o.w) + bfu2f(y.w));
            }
            *(ushort4*)(&As[rr * LDSP + ak4 * 4]) = o;
        }
        #pragma unroll
        for (int i = 0; i < 4; ++i) {
            int nn = bnr + i * 32;
            uint4 xv = *(const uint4*)((const unsigned short*)Wt +
                    (size_t)(bn + nn) * K + k0 + bk8 * 8);
            *(uint4*)(&Bs[nn * LDSP + bk8 * 8]) = xv;
        }
        __syncthreads();
        #pragma unroll
        for (int kk = 0; kk < 64; kk += 32) {
            short8 af[2], bf[4];
            #pragma unroll
            for (int mt = 0; mt < 2; ++mt)
                af[mt] = *(const short8*)(&As[(wm * 32 + mt * 16 + l15) * LDSP + kk + quad * 8]);
            #pragma unroll
            for (int nt = 0; nt < 4; ++nt)
                bf[nt] = *(const short8*)(&Bs[(wn * 64 + nt * 16 + l15) * LDSP + kk + quad * 8]);
            #pragma unroll
            for (int mt = 0; mt < 2; ++mt)
                #pragma unroll
                for (int nt = 0; nt < 4; ++nt)
                    acc[mt][nt] = __builtin_amdgcn_mfma_f32_16x16x32_bf16(
                        af[mt], bf[nt], acc[mt][nt], 0, 0, 0);
        }
        __syncthreads();
    }

    #pragma unroll
    for (int nt = 0; nt < 4; ++nt) {
        int gcol = bn + wn * 64 + nt * 16 + l15;
        float bv = (gcol < n1) ? ldin(bias1, bofs1 + gcol, isb)
                               : ldin(bias2, bofs2 + (gcol - n1), isb);
        #pragma unroll
        for (int mt = 0; mt < 2; ++mt) {
            #pragma unroll
            for (int r = 0; r < 4; ++r) {
                int grow = bm + wm * 32 + mt * 16 + quad * 4 + r;
                float v = acc[mt][nt][r] + bv;
                if (c_bf16)
                    ((__hip_bfloat16*)C)[(size_t)grow * ldc + gcol] = __float2bfloat16(v);
                else
                    ((float*)C)[(size_t)grow * ldc + gcol] = v;
            }
        }
    }
}

// ---------------------------------------------------------------------------
// deformable attention: one WAVE per row, 4 rows per block.
// XCD-contiguous block remap: round-robin XCD (= blk%8) gets a contiguous
// band of rows so its sampled v region stays L2-resident.
// cn layout [rl][j][h][c]; phase-1 store mapping h=lane&7 covers banks 0-31
// conflict-free; gather reads 2x ds_read_b128 (h-stride 32B, 2-way = free).
// ---------------------------------------------------------------------------
__global__ __launch_bounds__(256) void deform_kernel(
    const __hip_bfloat16* __restrict__ v,
    __hip_bfloat16* __restrict__ oa,
    int row0)
{
    __shared__ float sw[4][128];
    __shared__ __align__(16) int2 cn[4][16][8][4];   // [row][j][h][corner] {addr, wgt}

    const int tid = threadIdx.x;
    const int rl = tid >> 6, lane = tid & 63;
    // XCD-contiguous remap (grid divisible by 8)
    int nb = gridDim.x, f = blockIdx.x, blk = f;
    if ((nb & 7) == 0) blk = (f & 7) * (nb >> 3) + (f >> 3);
    const int lrow = blk * 4 + rl;
    const int row = lrow + row0;
    const int b = row / LQ_, q = row % LQ_;
    int lq, qy, qx; decode_q(q, lq, qy, qx);
    const size_t obase = (size_t)lrow * 384;
    const float sizes[4] = {64.f, 32.f, 16.f, 8.f};
    const int   dims[4]  = {64, 32, 16, 8};
    const int   starts[4] = {0, 4096, 5120, 5376};
    const float refx = (qx + 0.5f) / sizes[lq];
    const float refy = (qy + 0.5f) / sizes[lq];

    if (lane < 8) {
        float lg[16], mx = -1e30f;
        #pragma unroll
        for (int j = 0; j < 16; ++j) {
            lg[j] = __bfloat162float(oa[obase + 256 + lane * 16 + j]);
            mx = fmaxf(mx, lg[j]);
        }
        float s = 0.f;
        #pragma unroll
        for (int j = 0; j < 16; ++j) { lg[j] = __expf(lg[j] - mx); s += lg[j]; }
        float inv = 1.f / s;
        #pragma unroll
        for (int j = 0; j < 16; ++j) sw[rl][lane * 16 + j] = lg[j] * inv;
    }
    __syncthreads();

    #pragma unroll
    for (int t = 0; t < 2; ++t) {
        // lane -> (h = lane&7, j = (lane>>3)*2 + t): store group covers banks 0-31
        int h = lane & 7, j = ((lane >> 3) << 1) | t;
        int s = h * 16 + j;
        int l = j >> 2;
        int Wl = dims[l], st = starts[l];
        float siz = sizes[l];
        float ox = __bfloat162float(oa[obase + h * 32 + j * 2 + 0]);
        float oy = __bfloat162float(oa[obase + h * 32 + j * 2 + 1]);
        float x = refx * siz + ox - 0.5f;
        float y = refy * siz + oy - 0.5f;
        float x0f = floorf(x), y0f = floorf(y);
        int x0 = (int)x0f, y0 = (int)y0f;
        float wx = x - x0f, wy = y - y0f;
        float wq = sw[rl][s];
        int vbase = b * LQ_ + st;
        int2 tmp[4];
        #pragma unroll
        for (int c = 0; c < 4; ++c) {
            int cy = c >> 1, cx = c & 1;
            int yi = y0 + cy, xi = x0 + cx;
            float valid = (yi >= 0 && yi < Wl && xi >= 0 && xi < Wl) ? 1.f : 0.f;
            int yc = min(max(yi, 0), Wl - 1);
            int xc = min(max(xi, 0), Wl - 1);
            float cw = (cy ? wy : 1.f - wy) * (cx ? wx : 1.f - wx);
            float wgt = wq * cw * valid;
            int addr = (vbase + yc * Wl + xc) * 256 + h * 32;
            tmp[c] = make_int2(addr, __float_as_int(wgt));
        }
        *(int4*)&cn[rl][j][h][0] = *(int4*)&tmp[0];
        *(int4*)&cn[rl][j][h][2] = *(int4*)&tmp[2];
    }
    __syncthreads();

    {
        const int h = lane >> 3, dg = lane & 7;
        const unsigned short* vp = (const unsigned short*)v;
        // split accumulators (even/odd j) to shorten FMA dependency chains
        float e0 = 0.f, e1 = 0.f, e2 = 0.f, e3 = 0.f;
        float o0 = 0.f, o1 = 0.f, o2 = 0.f, o3 = 0.f;
        #pragma unroll 4
        for (int j = 0; j < 16; ++j) {
            int2 c4[4];
            *(int4*)&c4[0] = *(const int4*)&cn[rl][j][h][0];
            *(int4*)&c4[2] = *(const int4*)&cn[rl][j][h][2];
            #pragma unroll
            for (int c = 0; c < 4; ++c) {
                float wgt = __int_as_float(c4[c].y);
                uint2 u = *(const uint2*)(vp + c4[c].x + dg * 4);
                float f0 = __uint_as_float(u.x << 16);
                float f1 = __uint_as_float(u.x & 0xffff0000u);
                float f2 = __uint_as_float(u.y << 16);
                float f3 = __uint_as_float(u.y & 0xffff0000u);
                if (j & 1) { o0 += wgt * f0; o1 += wgt * f1; o2 += wgt * f2; o3 += wgt * f3; }
                else       { e0 += wgt * f0; e1 += wgt * f1; e2 += wgt * f2; e3 += wgt * f3; }
            }
        }
        ushort4 o;
        o.x = f2bfu(e0 + o0); o.y = f2bfu(e1 + o1);
        o.z = f2bfu(e2 + o2); o.w = f2bfu(e3 + o3);
        *(ushort4*)((unsigned short*)oa + obase + h * 32 + dg * 4) = o;
    }
}

// cast/copy to output
__global__ __launch_bounds__(256) void cast_kernel(
    const float* __restrict__ x, const unsigned short* __restrict__ xb,
    void* __restrict__ out, const int* __restrict__ dflag)
{
    size_t i = (size_t)blockIdx.x * 256 + threadIdx.x;
    if (*dflag) ((unsigned short*)out)[i] = xb[i];
    else        ((float*)out)[i] = x[i];
}

// ---------------------------------------------------------------------------
extern "C" void kernel_launch(void* const* d_in, const int* in_sizes, int n_in,
                              void* d_out, int out_size, void* d_ws, size_t ws_size,
                              hipStream_t stream)
{
    const void* s0 = d_in[0];  const void* p0 = d_in[1];
    const void* s1 = d_in[2];  const void* p1 = d_in[3];
    const void* s2 = d_in[4];  const void* p2 = d_in[5];
    const void* s3 = d_in[6];  const void* p3 = d_in[7];
    const void* lvl   = d_in[8];
    const void* Woff  = d_in[9];   const void* boff  = d_in[10];
    const void* Wattn = d_in[11];  const void* battn = d_in[12];
    const void* Wv    = d_in[13];  const void* bv    = d_in[14];
    const void* Wo    = d_in[15];  const void* bo    = d_in[16];
    const void* ln1g  = d_in[17];  const void* ln1b  = d_in[18];
    const void* Wfc1  = d_in[19];  const void* bfc1  = d_in[20];
    const void* Wfc2  = d_in[21];  const void* bfc2  = d_in[22];
    const void* ln2g  = d_in[23];  const void* ln2b  = d_in[24];

    // ---- workspace layout (bytes) ----
    char* base = (char*)d_ws;
    size_t off = 0;
    int* dflag = (int*)base;                 off += 256;
    float* cur = (float*)(base + off);       off += (size_t)M_ * 256 * 4;
    __hip_bfloat16* curb = (__hip_bfloat16*)(base + off); off += (size_t)M_ * 256 * 2;
    __hip_bfloat16* posb = (__hip_bfloat16*)(base + off); off += (size_t)M_ * 256 * 2;
    float* out1 = (float*)(base + off);      off += (size_t)M_ * 256 * 4;
    __hip_bfloat16* out1b = (__hip_bfloat16*)(base + off); off += (size_t)M_ * 256 * 2;
    __hip_bfloat16* Wt = (__hip_bfloat16*)(base + off);   off += (size_t)WL_ * NL_ * 2;
    off = (off + 255) & ~(size_t)255;
    __hip_bfloat16* vb = (__hip_bfloat16*)(base + off);
    size_t vbOff = off;                      off += (size_t)M_ * 256 * 2;
    off = (off + 255) & ~(size_t)255;
    __hip_bfloat16* pool = (__hip_bfloat16*)(base + off);
    size_t poolBytes   = (ws_size > off) ? ws_size - off : 0;
    size_t phase2Bytes = (ws_size > vbOff) ? ws_size - vbOff : 0;
    __hip_bfloat16* hid = vb;

    const int NCopt[8] = {1, 2, 5, 10, 17, 34, 85, 170};
    int NCd = 170, NCf = 170;
    for (int t = 0; t < 8; ++t)
        if ((size_t)(M_ / NCopt[t]) * 768 <= poolBytes) { NCd = NCopt[t]; break; }
    for (int t = 0; t < 8; ++t)
        if ((size_t)(M_ / NCopt[t]) * 2048 <= phase2Bytes) { NCf = NCopt[t]; break; }
    const int CHd = M_ / NCd, CHf = M_ / NCf;

    detect_kernel<<<1, 1, 0, stream>>>((const unsigned int*)ln1g, dflag);

    transpose_kernel<<<dim3(12, 8, NL_), 256, 0, stream>>>(
        Woff, 256 * 256, 256, Wattn, 256 * 128, 128, 256, Wt, WOFS_OAV, dflag);
    transpose_kernel<<<dim3(8, 8, NL_), 256, 0, stream>>>(
        Wv, 256 * 256, 256, nullptr, 0, 0, 256, Wt, WOFS_V, dflag);
    transpose_kernel<<<dim3(8, 8, NL_), 256, 0, stream>>>(
        Wo, 256 * 256, 256, nullptr, 0, 0, 256, Wt, WOFS_O, dflag);
    transpose_kernel<<<dim3(32, 8, NL_), 256, 0, stream>>>(
        Wfc1, 256 * 1024, 1024, nullptr, 0, 0, 256, Wt, WOFS_F1, dflag);
    transpose_kernel<<<dim3(8, 32, NL_), 256, 0, stream>>>(
        Wfc2, 1024 * 256, 256, nullptr, 0, 0, 1024, Wt, WOFS_F2, dflag);

    init_kernel<<<340, 256, 0, stream>>>(s0, s1, s2, s3, p0, p1, p2, p3, lvl,
                                         cur, curb, posb, dflag);

    for (int i = 0; i < NL_; ++i) {
        const __hip_bfloat16* WtL = Wt + (size_t)i * WL_;

        if (NCd == 1) {
            gemm_oav<<<5 * (M_ / 64), 256, 0, stream>>>(
                (const unsigned short*)curb, (const unsigned short*)posb,
                WtL + WOFS_OAV, boff, battn, bv, i,
                (unsigned short*)pool, (unsigned short*)vb, M_ / 64, dflag);
            deform_kernel<<<M_ / 4, 256, 0, stream>>>(vb, pool, 0);
            gemm_ln<<<M_ / 32, 256, 0, stream>>>(
                (const unsigned short*)pool, 384, WtL + WOFS_O,
                bo, (size_t)i * 256, cur, ln1g, ln1b, (size_t)i * 256,
                out1, out1b, 256, dflag);
        } else {
            gemm_mfma64<<<2 * (M_ / 64), 256, 0, stream>>>(
                (const unsigned short*)curb, 256, nullptr, WtL + WOFS_V,
                bv, (size_t)i * 256, 256, nullptr, 0,
                vb, 1, 256, 256, 256, M_ / 64, 2, dflag);
            for (int c = 0; c < NCd; ++c) {
                size_t r0 = (size_t)c * CHd;
                gemm_mfma64<<<3 * (CHd / 64), 256, 0, stream>>>(
                    (const unsigned short*)curb + r0 * 256, 256,
                    (const unsigned short*)posb + r0 * 256, WtL + WOFS_OAV,
                    boff, (size_t)i * 256, 256, battn, (size_t)i * 128,
                    pool, 1, 384, 384, 256, CHd / 64, 3, dflag);
                deform_kernel<<<CHd / 4, 256, 0, stream>>>(vb, pool, (int)r0);
                gemm_ln<<<CHd / 32, 256, 0, stream>>>(
                    (const unsigned short*)pool, 384, WtL + WOFS_O,
                    bo, (size_t)i * 256, cur + r0 * 256, ln1g, ln1b, (size_t)i * 256,
                    out1 + r0 * 256, out1b + r0 * 256, 256, dflag);
            }
        }

        for (int c = 0; c < NCf; ++c) {
            size_t r0 = (size_t)c * CHf;
            gemm_mfma<<<8 * (CHf / 128), 256, 0, stream>>>(
                (const unsigned short*)out1b + r0 * 256, 256, WtL + WOFS_F1,
                bfc1, (size_t)i * 1024, hid, 1, 1024, 1024, 256, 1,
                CHf / 128, 8, dflag);
            gemm_ln<<<CHf / 32, 256, 0, stream>>>(
                (const unsigned short*)hid, 1024, WtL + WOFS_F2,
                bfc2, (size_t)i * 256, out1 + r0 * 256, ln2g, ln2b, (size_t)i * 256,
                cur + r0 * 256, curb + r0 * 256, 1024, dflag);
        }
    }

    cast_kernel<<<(M_ * 256) / 256, 256, 0, stream>>>(
        cur, (const unsigned short*)curb, d_out, dflag);
}